// Round 4
// baseline (280.308 us; speedup 1.0000x reference)
//
#include <hip/hip_runtime.h>
#include <hip/hip_bf16.h>
#include <hip/hip_fp16.h>
#include <hip/hip_cooperative_groups.h>

namespace cg = cooperative_groups;

#define IMG      512
#define ROW_F4   128                 // float4 per image row
#define PLANE_F4 65536               // float4 per channel plane
#define NB       32
#define NC       3
#define TILE_W   128
#define TILE_H   16
#define NT       4                   // tiles per block = one 512x16 band
#define LDS_ROWS (TILE_H + 2)        // 18
#define LDS_F4_W 34                  // f4 per staged row (halo included)
#define LDS_F_W  (LDS_F4_W * 4)      // 136 floats

// Fused: gray -> sobel magnitude (kept in LDS as fp16) -> per-image max
// -> grid sync -> normalize -> broadcast to 3 channels. One dispatch.
__global__ __launch_bounds__(256, 4) void sobel_fused_kernel(
    const float* __restrict__ in, float* __restrict__ out,
    unsigned int* __restrict__ maxbuf)
{
    __shared__ float4 g4[LDS_ROWS * LDS_F4_W];   // 9792 B gray staging
    __shared__ short4 magl4[NT * 512];           // 16384 B fp16 magnitudes
    __shared__ float  wred[4];
    float*  g    = (float*)g4;
    __half* magl = (__half*)magl4;

    const int tid  = threadIdx.x;
    const int b    = blockIdx.x >> 5;            // image  [0,32)
    const int band = blockIdx.x & 31;            // y-band [0,32)
    const int ty0  = band * TILE_H;

    const float4* base4 = (const float4*)in + (size_t)b * NC * PLANE_F4;

    float lmax = 0.0f;

    // ---------------- Phase 1: sobel magnitude per tile -> LDS ----------------
    for (int t = 0; t < NT; ++t) {
        const int tx0   = t * TILE_W;
        const int tx0_4 = tx0 >> 2;

        // Stage gray tile + halo (proven r2 code): float4 loads of 3 planes.
        #pragma unroll
        for (int k = 0; k < 3; ++k) {
            int idx = tid + k * 256;
            if (idx < LDS_ROWS * LDS_F4_W) {
                int row = idx / LDS_F4_W;
                int col = idx - row * LDS_F4_W;
                int gy  = ty0 + row - 1;
                int gx4 = tx0_4 + col - 1;
                float4 v = make_float4(0.f, 0.f, 0.f, 0.f);
                if (gy >= 0 && gy < IMG && gx4 >= 0 && gx4 < ROW_F4) {
                    const float4* p = base4 + (size_t)gy * ROW_F4 + gx4;
                    float4 a = p[0];
                    float4 c = p[PLANE_F4];
                    float4 d = p[2 * PLANE_F4];
                    v = make_float4((a.x + c.x + d.x) * (1.0f / 3.0f),
                                    (a.y + c.y + d.y) * (1.0f / 3.0f),
                                    (a.z + c.z + d.z) * (1.0f / 3.0f),
                                    (a.w + c.w + d.w) * (1.0f / 3.0f));
                }
                g4[idx] = v;
            }
        }
        __syncthreads();

        // 8 scalar outputs per thread; consecutive lanes -> consecutive LDS floats.
        #pragma unroll
        for (int kk = 0; kk < 8; ++kk) {
            int p  = tid + kk * 256;             // [0, 2048)
            int oy = p >> 7;
            int ox = p & 127;
            const float* r0 = g + (oy    ) * LDS_F_W + ox + 3;
            const float* r1 = g + (oy + 1) * LDS_F_W + ox + 3;
            const float* r2 = g + (oy + 2) * LDS_F_W + ox + 3;
            float a00 = r0[0], a01 = r0[1], a02 = r0[2];
            float a10 = r1[0],             a12 = r1[2];
            float a20 = r2[0], a21 = r2[1], a22 = r2[2];
            float sx = (a02 - a00) + 2.0f * (a12 - a10) + (a22 - a20);
            float sy = (a20 - a00) + 2.0f * (a21 - a01) + (a22 - a02);
            float mag = sqrtf(sx * sx + sy * sy);
            magl[t * 2048 + p] = __float2half(mag);
            lmax = fmaxf(lmax, mag);
        }
        __syncthreads();   // protect g4 before next tile's staging
    }

    // Block max -> per-image atomicMax (mag >= 0: uint order == float order).
    #pragma unroll
    for (int off = 32; off; off >>= 1)
        lmax = fmaxf(lmax, __shfl_down(lmax, off, 64));
    if ((tid & 63) == 0) wred[tid >> 6] = lmax;
    __syncthreads();
    if (tid == 0) {
        float mb = fmaxf(fmaxf(wred[0], wred[1]), fmaxf(wred[2], wred[3]));
        atomicMax(&maxbuf[b], __float_as_uint(mb));
    }

    // ---------------- Grid-wide sync ----------------
    cg::this_grid().sync();

    // Atomic read of the finished per-image max, broadcast via LDS.
    if (tid == 0) wred[0] = __uint_as_float(atomicMax(&maxbuf[b], 0u));
    __syncthreads();
    const float inv = 1.0f / (wred[0] + 1e-6f);

    // ---------------- Phase 2: normalize from LDS, write 3 channels ----------------
    float4* o0 = (float4*)out + (size_t)b * NC * PLANE_F4;
    #pragma unroll
    for (int t = 0; t < NT; ++t) {
        const int tx0_4 = t * (TILE_W / 4);
        #pragma unroll
        for (int k = 0; k < 2; ++k) {
            int fi  = k * 256 + tid;             // [0,512) f4 within tile
            int row = fi >> 5;                   // tile row (32 f4 per tile row)
            int col = fi & 31;
            short4 h = magl4[t * 512 + fi];
            const __half* hp = (const __half*)&h;
            float4 v = make_float4(__half2float(hp[0]) * inv,
                                   __half2float(hp[1]) * inv,
                                   __half2float(hp[2]) * inv,
                                   __half2float(hp[3]) * inv);
            size_t o = (size_t)(ty0 + row) * ROW_F4 + tx0_4 + col;
            o0[o]                = v;
            o0[o + PLANE_F4]     = v;
            o0[o + 2 * PLANE_F4] = v;
        }
    }
}

extern "C" void kernel_launch(void* const* d_in, const int* in_sizes, int n_in,
                              void* d_out, int out_size, void* d_ws, size_t ws_size,
                              hipStream_t stream)
{
    const float*  in     = (const float*)d_in[0];
    float*        out    = (float*)d_out;
    unsigned int* maxbuf = (unsigned int*)d_ws;      // 32 * 4 = 128 bytes

    hipMemsetAsync(maxbuf, 0, NB * sizeof(unsigned int), stream);

    void* args[3] = { (void*)&in, (void*)&out, (void*)&maxbuf };
    hipLaunchCooperativeKernel((const void*)sobel_fused_kernel,
                               dim3(NB * 32, 1, 1), dim3(256, 1, 1),
                               args, 0, stream);
}

// Round 9
// 210.880 us; speedup vs baseline: 1.3292x; 1.3292x over previous
//
#include <hip/hip_runtime.h>
#include <hip/hip_bf16.h>
#include <hip/hip_fp16.h>

#define IMG      512
#define ROW_F4   128                 // float4 per image row
#define PLANE_F4 65536               // float4 per channel plane
#define HW       (IMG * IMG)
#define NB       32
#define NC       3
#define TILE_W   128
#define TILE_H   16
#define LDS_ROWS (TILE_H + 2)        // 18
#define LDS_F4_W 34
#define LDS_F_W  (LDS_F4_W * 4)      // 136 floats
#define MAG_BYTES ((size_t)NB * HW * 2)   // 16 MiB fp16 magnitude

typedef float vf4 __attribute__((ext_vector_type(4)));   // clang-native for nontemporal

// ---------------- fp16-scratch path ----------------

// k1: gray -> sobel -> packed fp16 magnitude pairs in ws, per-image max.
__global__ __launch_bounds__(256) void sobel_mag_f16(
    const float* __restrict__ in, unsigned int* __restrict__ mag,
    unsigned int* __restrict__ maxbuf)
{
    __shared__ float4 g4[LDS_ROWS * LDS_F4_W];
    __shared__ float wmax[4];
    float* g = (float*)g4;

    const int b   = blockIdx.z;
    const int tx0 = blockIdx.x * TILE_W;
    const int ty0 = blockIdx.y * TILE_H;
    const int tid = threadIdx.x;

    const float4* base4 = (const float4*)in + (size_t)b * NC * PLANE_F4;
    const int tx0_4 = tx0 >> 2;

    // Stage gray tile + halo (proven r2 staging).
    #pragma unroll
    for (int k = 0; k < 3; ++k) {
        int idx = tid + k * 256;
        if (idx < LDS_ROWS * LDS_F4_W) {
            int row = idx / LDS_F4_W;
            int col = idx - row * LDS_F4_W;
            int gy  = ty0 + row - 1;
            int gx4 = tx0_4 + col - 1;
            float4 v = make_float4(0.f, 0.f, 0.f, 0.f);
            if (gy >= 0 && gy < IMG && gx4 >= 0 && gx4 < ROW_F4) {
                const float4* p = base4 + (size_t)gy * ROW_F4 + gx4;
                float4 a = p[0];
                float4 c = p[PLANE_F4];
                float4 d = p[2 * PLANE_F4];
                v = make_float4((a.x + c.x + d.x) * (1.0f / 3.0f),
                                (a.y + c.y + d.y) * (1.0f / 3.0f),
                                (a.z + c.z + d.z) * (1.0f / 3.0f),
                                (a.w + c.w + d.w) * (1.0f / 3.0f));
            }
            g4[idx] = v;
        }
    }
    __syncthreads();

    float lmax = 0.0f;
    // packed-pair magnitude plane: 256 uints per image row
    unsigned int* magb = mag + (size_t)b * (HW / 2)
                             + (size_t)ty0 * (IMG / 2) + (tx0 >> 1);

    #pragma unroll
    for (int kk = 0; kk < 4; ++kk) {
        int pp  = tid + kk * 256;        // pair index in tile [0,1024)
        int oy  = pp >> 6;               // tile row  [0,16)
        int oxp = pp & 63;               // pair col  [0,64)
        int ox  = oxp << 1;              // left px col (even)
        const float* r0 = g + oy * LDS_F_W + ox + 3;   // gray row oy-1
        const float* r1 = r0 + LDS_F_W;                // gray row oy
        const float* r2 = r1 + LDS_F_W;                // gray row oy+1
        float a0 = r0[0], a1 = r0[1], a2 = r0[2], a3 = r0[3];
        float b0 = r1[0], b1 = r1[1], b2 = r1[2], b3 = r1[3];
        float c0 = r2[0], c1 = r2[1], c2 = r2[2], c3 = r2[3];

        float sx0 = (a2 - a0) + 2.0f * (b2 - b0) + (c2 - c0);
        float sy0 = (c0 - a0) + 2.0f * (c1 - a1) + (c2 - a2);
        float m0  = sqrtf(sx0 * sx0 + sy0 * sy0);
        float sx1 = (a3 - a1) + 2.0f * (b3 - b1) + (c3 - c1);
        float sy1 = (c1 - a1) + 2.0f * (c2 - a2) + (c3 - a3);
        float m1  = sqrtf(sx1 * sx1 + sy1 * sy1);

        lmax = fmaxf(lmax, fmaxf(m0, m1));
        union { __half h[2]; unsigned int u; } pk;
        pk.h[0] = __float2half(m0);
        pk.h[1] = __float2half(m1);
        magb[oy * (IMG / 2) + oxp] = pk.u;
    }

    #pragma unroll
    for (int off = 32; off; off >>= 1)
        lmax = fmaxf(lmax, __shfl_down(lmax, off, 64));
    if ((tid & 63) == 0) wmax[tid >> 6] = lmax;
    __syncthreads();
    if (tid == 0) {
        float mb = fmaxf(fmaxf(wmax[0], wmax[1]), fmaxf(wmax[2], wmax[3]));
        atomicMax(&maxbuf[b], __float_as_uint(mb));  // mag >= 0
    }
}

// k2: 4 independent uint2 fp16 loads per thread, 12 dense f4 stores (nontemporal).
__global__ __launch_bounds__(256) void normalize_f16(
    const uint2* __restrict__ mag, float* __restrict__ out,
    const unsigned int* __restrict__ maxbuf)
{
    const int t = blockIdx.x * 256 + threadIdx.x;    // [0, 524288)
    vf4* o4 = (vf4*)out;

    uint2 v[4];
    #pragma unroll
    for (int k = 0; k < 4; ++k)
        v[k] = mag[(size_t)t + (size_t)k * 524288];  // job j = t + k*524288

    #pragma unroll
    for (int k = 0; k < 4; ++k) {
        int j   = t + k * 524288;                    // f4 job [0, 2097152)
        int b   = j >> 16;                           // image (uniform per block)
        int hw4 = j & (PLANE_F4 - 1);
        float inv = 1.0f / (__uint_as_float(maxbuf[b]) + 1e-6f);

        union { uint2 u; __half h[4]; } m; m.u = v[k];
        vf4 f = { __half2float(m.h[0]) * inv,
                  __half2float(m.h[1]) * inv,
                  __half2float(m.h[2]) * inv,
                  __half2float(m.h[3]) * inv };
        size_t base = (size_t)b * NC * PLANE_F4 + hw4;
        __builtin_nontemporal_store(f, &o4[base]);
        __builtin_nontemporal_store(f, &o4[base + PLANE_F4]);
        __builtin_nontemporal_store(f, &o4[base + 2 * PLANE_F4]);
    }
}

// ---------------- fallback path (r2 verbatim, f32 mag via out ch0) ----------------

__global__ __launch_bounds__(256) void sobel_mag_f32(
    const float* __restrict__ in, float* __restrict__ out,
    unsigned int* __restrict__ maxbuf)
{
    __shared__ float4 g4[LDS_ROWS * LDS_F4_W];
    __shared__ float wmax[4];
    float* g = (float*)g4;

    const int b   = blockIdx.z;
    const int tx0 = blockIdx.x * TILE_W;
    const int ty0 = blockIdx.y * TILE_H;
    const int tid = threadIdx.x;

    const float4* base4 = (const float4*)in + (size_t)b * NC * PLANE_F4;
    const int tx0_4 = tx0 >> 2;
    #pragma unroll
    for (int k = 0; k < 3; ++k) {
        int idx = tid + k * 256;
        if (idx < LDS_ROWS * LDS_F4_W) {
            int row = idx / LDS_F4_W;
            int col = idx - row * LDS_F4_W;
            int gy  = ty0 + row - 1;
            int gx4 = tx0_4 + col - 1;
            float4 v = make_float4(0.f, 0.f, 0.f, 0.f);
            if (gy >= 0 && gy < IMG && gx4 >= 0 && gx4 < ROW_F4) {
                const float4* p = base4 + (size_t)gy * ROW_F4 + gx4;
                float4 a = p[0];
                float4 c = p[PLANE_F4];
                float4 d = p[2 * PLANE_F4];
                v = make_float4((a.x + c.x + d.x) * (1.0f / 3.0f),
                                (a.y + c.y + d.y) * (1.0f / 3.0f),
                                (a.z + c.z + d.z) * (1.0f / 3.0f),
                                (a.w + c.w + d.w) * (1.0f / 3.0f));
            }
            g4[idx] = v;
        }
    }
    __syncthreads();

    float lmax = 0.0f;
    float* outb = out + (size_t)b * NC * HW;
    #pragma unroll
    for (int kk = 0; kk < 8; ++kk) {
        int p  = tid + kk * 256;
        int oy = p >> 7;
        int ox = p & 127;
        const float* r0 = g + (oy    ) * LDS_F_W + ox + 3;
        const float* r1 = g + (oy + 1) * LDS_F_W + ox + 3;
        const float* r2 = g + (oy + 2) * LDS_F_W + ox + 3;
        float a00 = r0[0], a01 = r0[1], a02 = r0[2];
        float a10 = r1[0],             a12 = r1[2];
        float a20 = r2[0], a21 = r2[1], a22 = r2[2];
        float sx = (a02 - a00) + 2.0f * (a12 - a10) + (a22 - a20);
        float sy = (a20 - a00) + 2.0f * (a21 - a01) + (a22 - a02);
        float mag = sqrtf(sx * sx + sy * sy);
        outb[(size_t)(ty0 + oy) * IMG + (tx0 + ox)] = mag;
        lmax = fmaxf(lmax, mag);
    }
    #pragma unroll
    for (int off = 32; off; off >>= 1)
        lmax = fmaxf(lmax, __shfl_down(lmax, off, 64));
    if ((tid & 63) == 0) wmax[tid >> 6] = lmax;
    __syncthreads();
    if (tid == 0) {
        float mb = fmaxf(fmaxf(wmax[0], wmax[1]), fmaxf(wmax[2], wmax[3]));
        atomicMax(&maxbuf[b], __float_as_uint(mb));
    }
}

__global__ __launch_bounds__(256) void normalize_f32(
    float* __restrict__ out, const unsigned int* __restrict__ maxbuf)
{
    const int b     = blockIdx.x >> 6;
    const int chunk = blockIdx.x & 63;
    const float inv = 1.0f / (__uint_as_float(maxbuf[b]) + 1e-6f);
    float4* c0 = (float4*)out + (size_t)b * NC * PLANE_F4;
    #pragma unroll
    for (int k = 0; k < 4; ++k) {
        int i = chunk * 1024 + k * 256 + threadIdx.x;
        float4 m = c0[i];
        float4 v = make_float4(m.x * inv, m.y * inv, m.z * inv, m.w * inv);
        c0[i] = v;
        c0[i + PLANE_F4] = v;
        c0[i + 2 * PLANE_F4] = v;
    }
}

extern "C" void kernel_launch(void* const* d_in, const int* in_sizes, int n_in,
                              void* d_out, int out_size, void* d_ws, size_t ws_size,
                              hipStream_t stream)
{
    const float* in  = (const float*)d_in[0];
    float*       out = (float*)d_out;

    if (ws_size >= MAG_BYTES + 128) {
        unsigned int* mag    = (unsigned int*)d_ws;
        unsigned int* maxbuf = (unsigned int*)((char*)d_ws + MAG_BYTES);
        (void)hipMemsetAsync(maxbuf, 0, NB * sizeof(unsigned int), stream);
        dim3 grid1(IMG / TILE_W, IMG / TILE_H, NB);      // (4, 32, 32)
        sobel_mag_f16<<<grid1, dim3(256), 0, stream>>>(in, mag, maxbuf);
        normalize_f16<<<dim3(2048), dim3(256), 0, stream>>>(
            (const uint2*)mag, out, maxbuf);
    } else {
        unsigned int* maxbuf = (unsigned int*)d_ws;
        (void)hipMemsetAsync(maxbuf, 0, NB * sizeof(unsigned int), stream);
        dim3 grid1(IMG / TILE_W, IMG / TILE_H, NB);
        sobel_mag_f32<<<grid1, dim3(256), 0, stream>>>(in, out, maxbuf);
        normalize_f32<<<dim3(NB * 64), dim3(256), 0, stream>>>(out, maxbuf);
    }
}